// Round 9
// baseline (337.248 us; speedup 1.0000x reference)
//
#include <hip/hip_runtime.h>

// ---------------------------------------------------------------------------
// GATBottleneck (ALL I/O fp32; compute bf16 MFMA, fp32 accum)
//
//  1. trcvt: x fp32 NCHW -> xt bf16 [16384][1024]
//  2. trcvt: WgT2 bf16 [4096][512]; WgT2[hj][c] = w_gat[c][hj]
//  3. cvt  : w_reduce, w_restore fp32 -> bf16 (already B^T layout)
//  4. gemm<1>: xr = relu(bn(xt @ w_reduce^T))          [16384][512] bf16
//  5. attproj: P[s][h][c] = sum_t w_gat[c][h*512+t]*att_s[h][t]   (fp32)
//  6. att    : a_s[n][h] = xr[n] . P[s][h]                        (fp32)
//  7. yagg   : FUSED per-(image, 64-col-tile) block: for each head h,
//              Y_h-tile[256][64] = xr_img @ W_h^T  (MFMA, dbuf LDS, swizzle)
//              -> LDS -> alpha-weighted 5-pt row stencil -> gacc (fp32).
//              gat = sum_h stencil_h(Y_h)/8 + bias.  Y NEVER hits HBM.
//  8. gemm<3>: out = relu(bn(gat @ w_restore^T) + x)   -> fp32 NCHW
// edge_index is the fixed 4-neighbor grid + self loops -> analytic.
// ---------------------------------------------------------------------------

typedef unsigned short u16;
typedef __attribute__((ext_vector_type(4))) unsigned short u16x4;
typedef __attribute__((ext_vector_type(8))) unsigned short u16x8;
typedef __attribute__((ext_vector_type(8))) __bf16 bf16x8;
typedef __attribute__((ext_vector_type(4))) float f32x4;

#define B_    64
#define CIN   1024
#define CRED  512
#define COUT  1024
#define NPIX  256
#define HEADS 8
#define KGAT  4096
#define MTOT  16384
#define EPSB  1e-5f

__device__ __forceinline__ float b2f(u16 u) {
  union { unsigned u; float f; } c; c.u = ((unsigned)u) << 16; return c.f;
}
__device__ __forceinline__ u16 f2b(float f) {
  union { float f; unsigned u; } c; c.f = f;
  unsigned r = (c.u + 0x7FFFu + ((c.u >> 16) & 1u)) >> 16;
  return (u16)r;
}

__device__ __forceinline__ void gload_lds16(const void* g, void* lds) {
  __builtin_amdgcn_global_load_lds(
      (const __attribute__((address_space(1))) void*)g,
      (__attribute__((address_space(3))) void*)lds, 16, 0, 0);
}

// ================== FUSED projection + GAT aggregation =====================
// Block = (image img, col-tile ct of 64 gat columns).  512 threads, 8 waves.
// Per head h: GEMM  Y = xr[img rows 0..255] @ WgT2[h*512+ct*64 .., :]^T
//   (K=512, 16 K-tiles, double-buffered LDS, R6 swizzle, swapped-operand
//    MFMA: acc[fm][fn] reg r <-> row w*32+fm*16+l15, col fn*16+l4*4+r)
// then Y -> LDS [256][72] bf16, then per-node 5-edge stencil with alpha
// (precomputed fp32 in LDS) accumulating gacc.  Epilogue adds gat_bias.
// LDS (u16 units): A dbuf 2x8192 @0 | B dbuf 2x2048 @16384 | Y 18432 @20480
//   | alpha 10240 f32 (=20480 u16) @38912  => 59392 u16 = 118784 B total.
//   (R8 bug: requested only 96 KiB -> alf OOB for n>=128 -> alpha read 0.)
__global__ __launch_bounds__(512, 1) void yagg_kernel(
    const u16* __restrict__ xr, const u16* __restrict__ WgT2,
    const float* __restrict__ a_all, const float* __restrict__ gat_bias,
    u16* __restrict__ gat)
{
  extern __shared__ u16 lds[];
  u16*   As  = lds;                      // 2 x 8192
  u16*   Bs  = lds + 16384;              // 2 x 2048
  u16*   Ys  = lds + 20480;              // [256][72]
  float* alf = (float*)(lds + 38912);    // [256][5][8] fp32 = 40960 B

  const int tid = threadIdx.x;
  const int w = tid >> 6, lane = tid & 63;
  const int l15 = lane & 15, l4 = lane >> 4;

  // bid bits: img = (bid&7)<<3 | bid>>6 (bijective), ct = (bid>>3)&7.
  const int bid = blockIdx.x;
  const int img = ((bid & 7) << 3) | (bid >> 6);
  const int ct  = (bid >> 3) & 7;

  const size_t nbase = (size_t)img * NPIX;
  const u16* gA = xr + nbase * 512;

  // ---- alpha precompute: 2048 (n,h) softmaxes, 4 per thread ----
  const float* a_src = a_all;
  const float* a_dst = a_all + (size_t)MTOT * HEADS;
#pragma unroll
  for (int i = 0; i < 4; ++i) {
    const int nh = tid + i * 512;
    const int n = nh >> 3, h = nh & 7;
    const int gi = n >> 4, gj = n & 15;
    int vv[5];
    vv[0] = n;
    vv[1] = (gi > 0)  ? n - 16 : -1;
    vv[2] = (gi < 15) ? n + 16 : -1;
    vv[3] = (gj > 0)  ? n - 1  : -1;
    vv[4] = (gj < 15) ? n + 1  : -1;
    const float ad = a_dst[(nbase + n) * HEADS + h];
    float l[5]; float mx = -1e30f;
#pragma unroll
    for (int e = 0; e < 5; ++e) {
      if (vv[e] >= 0) {
        const float xx = a_src[(nbase + vv[e]) * HEADS + h] + ad;
        l[e] = xx > 0.f ? xx : 0.2f * xx;   // leaky_relu(0.2)
        mx = fmaxf(mx, l[e]);
      } else l[e] = -1e30f;
    }
    float s = 0.f, ee[5];
#pragma unroll
    for (int e = 0; e < 5; ++e) {
      ee[e] = (vv[e] >= 0) ? __expf(l[e] - mx) : 0.f;
      s += ee[e];
    }
    const float inv = 0.125f / s;   // head-mean folded
#pragma unroll
    for (int e = 0; e < 5; ++e) alf[n * 40 + e * 8 + h] = ee[e] * inv;
  }

  // ---- staging maps (R6-verified swizzle: chunk kb ^= (row>>1)&3) ----
  int offA[2], dstA[2];
#pragma unroll
  for (int i = 0; i < 2; ++i) {
    const int f = i * 512 + tid;       // A chunk 0..1023
    const int r = f >> 2;
    offA[i] = r * 512 + ((f & 3) ^ ((r >> 1) & 3)) * 8;
    dstA[i] = (i * 512 + w * 64) * 8;  // linear LDS dest (wave base + lane*16B)
  }
  const int gch = w * 64 + lane;       // B chunk 0..255 (waves 0-3 only)
  const int brow = gch >> 2;
  const int offB = brow * 512 + ((gch & 3) ^ ((brow >> 1) & 3)) * 8;
  const int dstB = w * 64 * 8;

  const int sw = (l15 >> 1) & 3;
  const int fragOff = l15 * 32 + (l4 ^ sw) * 8;  // + rowbase*32

  f32x4 gacc[2][4];
#pragma unroll
  for (int i = 0; i < 2; ++i)
#pragma unroll
    for (int j = 0; j < 4; ++j) gacc[i][j] = f32x4{0.f, 0.f, 0.f, 0.f};

#pragma unroll 1
  for (int h = 0; h < 8; ++h) {
    const u16* gB = WgT2 + (size_t)(h * 512 + ct * 64) * 512;
    f32x4 acc[2][4];
#pragma unroll
    for (int i = 0; i < 2; ++i)
#pragma unroll
      for (int j = 0; j < 4; ++j) acc[i][j] = f32x4{0.f, 0.f, 0.f, 0.f};

    // prologue: stage kt=0 -> buf 0
    gload_lds16(gA + offA[0], &As[dstA[0]]);
    gload_lds16(gA + offA[1], &As[dstA[1]]);
    if (w < 4) gload_lds16(gB + offB, &Bs[dstB]);

#pragma unroll 1
    for (int kt = 0; kt < 16; ++kt) {
      __syncthreads();                       // drains vmcnt: buf kt&1 ready
      const int cb = (kt & 1) * 8192, cbB = (kt & 1) * 2048;
      if (kt < 15) {                          // stage kt+1 -> other buf
        const int nb = ((kt + 1) & 1) * 8192, nbB = ((kt + 1) & 1) * 2048;
        const int ko = (kt + 1) * 32;
        gload_lds16(gA + ko + offA[0], &As[nb + dstA[0]]);
        gload_lds16(gA + ko + offA[1], &As[nb + dstA[1]]);
        if (w < 4) gload_lds16(gB + ko + offB, &Bs[nbB + dstB]);
      }
      bf16x8 af[2], bfr[4];
      af[0] = *(const bf16x8*)&As[cb + (w * 32) * 32 + fragOff];
      af[1] = *(const bf16x8*)&As[cb + (w * 32 + 16) * 32 + fragOff];
#pragma unroll
      for (int fn = 0; fn < 4; ++fn)
        bfr[fn] = *(const bf16x8*)&Bs[cbB + (fn * 16) * 32 + fragOff];
      __builtin_amdgcn_s_setprio(1);
#pragma unroll
      for (int fm = 0; fm < 2; ++fm)
#pragma unroll
        for (int fn = 0; fn < 4; ++fn)
          acc[fm][fn] = __builtin_amdgcn_mfma_f32_16x16x32_bf16(
              bfr[fn], af[fm], acc[fm][fn], 0, 0, 0);
      __builtin_amdgcn_s_setprio(0);
    }
    __syncthreads();   // all waves done reading bufs & MFMA complete

    // Y tile -> LDS (stride 72 u16 = 144B -> ~2-way banks)
#pragma unroll
    for (int fm = 0; fm < 2; ++fm)
#pragma unroll
      for (int fn = 0; fn < 4; ++fn) {
        u16x4 yv;
#pragma unroll
        for (int r = 0; r < 4; ++r) yv[r] = f2b(acc[fm][fn][r]);
        *(u16x4*)&Ys[(w * 32 + fm * 16 + l15) * 72 + fn * 16 + l4 * 4] = yv;
      }
    __syncthreads();   // Y visible to all

    // stencil: gacc[n][c] += sum_e alpha[n][e][h] * Y[v_e(n)][c]
#pragma unroll
    for (int fm = 0; fm < 2; ++fm) {
      const int n = w * 32 + fm * 16 + l15;
      const int gi = n >> 4, gj = n & 15;
      int vv[5];
      vv[0] = n;
      vv[1] = (gi > 0)  ? n - 16 : n;   // invalid -> alpha==0, read self
      vv[2] = (gi < 15) ? n + 16 : n;
      vv[3] = (gj > 0)  ? n - 1  : n;
      vv[4] = (gj < 15) ? n + 1  : n;
#pragma unroll
      for (int e = 0; e < 5; ++e) {
        const float a = alf[n * 40 + e * 8 + h];
#pragma unroll
        for (int fn = 0; fn < 4; ++fn) {
          const u16x4 yv = *(const u16x4*)&Ys[vv[e] * 72 + fn * 16 + l4 * 4];
#pragma unroll
          for (int r = 0; r < 4; ++r) gacc[fm][fn][r] += a * b2f(yv[r]);
        }
      }
    }
    __syncthreads();   // stencil done before next head rewrites Ys
  }

  // epilogue: gat[(img*256 + row)][ct*64 + col] = gacc + bias
#pragma unroll
  for (int fm = 0; fm < 2; ++fm) {
    const size_t grow = (nbase + w * 32 + fm * 16 + l15) * (size_t)CRED;
#pragma unroll
    for (int fn = 0; fn < 4; ++fn) {
      const int col = ct * 64 + fn * 16 + l4 * 4;
      const float4 bb = *(const float4*)&gat_bias[col];
      u16x4 ov;
      ov[0] = f2b(gacc[fm][fn][0] + bb.x);
      ov[1] = f2b(gacc[fm][fn][1] + bb.y);
      ov[2] = f2b(gacc[fm][fn][2] + bb.z);
      ov[3] = f2b(gacc[fm][fn][3] + bb.w);
      *(u16x4*)&gat[grow + col] = ov;
    }
  }
}

// ------------- 64x64 transpose fp32 -> bf16 --------------------------------
__global__ __launch_bounds__(256) void trcvt_kernel(
    const float* __restrict__ src, u16* __restrict__ dst,
    int srs, int drs, long szs, long dzs)
{
  __shared__ float tile[64][65];
  const int t = threadIdx.x;
  const int tr = t >> 4, tc = (t & 15) * 4;
  const long sbase = (long)blockIdx.z * szs +
                     (long)(blockIdx.y * 64) * srs + blockIdx.x * 64;
#pragma unroll
  for (int i = 0; i < 4; ++i) {
    const int r = i * 16 + tr;
    const float4 v = *(const float4*)&src[sbase + (long)r * srs + tc];
    tile[r][tc]     = v.x;
    tile[r][tc + 1] = v.y;
    tile[r][tc + 2] = v.z;
    tile[r][tc + 3] = v.w;
  }
  __syncthreads();
  const long dbase = (long)blockIdx.z * dzs +
                     (long)(blockIdx.x * 64) * drs + blockIdx.y * 64;
#pragma unroll
  for (int i = 0; i < 4; ++i) {
    const int c = i * 16 + tr;
    u16x4 o;
#pragma unroll
    for (int q = 0; q < 4; ++q) o[q] = f2b(tile[tc + q][c]);
    *(u16x4*)&dst[dbase + (long)c * drs + tc] = o;
  }
}

// --------------------- elementwise fp32 -> bf16 convert --------------------
__global__ __launch_bounds__(256) void cvt_kernel(
    const float* __restrict__ src, u16* __restrict__ dst)
{
  const int i = (blockIdx.x * 256 + threadIdx.x) * 8;
  const float4 a = *(const float4*)&src[i];
  const float4 b = *(const float4*)&src[i + 4];
  u16x8 o;
  o[0] = f2b(a.x); o[1] = f2b(a.y); o[2] = f2b(a.z); o[3] = f2b(a.w);
  o[4] = f2b(b.x); o[5] = f2b(b.y); o[6] = f2b(b.z); o[7] = f2b(b.w);
  *(u16x8*)&dst[i] = o;
}

// ------------------------- 128x128 MFMA GEMM -------------------------------
// MODE 1: out16 = relu(bn(C)) bf16 row-major   (pg..pv fp32, len Nloc)
// MODE 3: out32 = relu(bn(C) + auxf) fp32 NCHW (auxf = x residual)
#define BM 128
#define BN 128
#define BK 32

template <int MODE>
__global__ __launch_bounds__(256, 2) void gemm_kernel(
    const u16* __restrict__ A, const u16* __restrict__ Bt,
    u16* __restrict__ out16, float* __restrict__ out32,
    const float* __restrict__ pg, const float* __restrict__ pb,
    const float* __restrict__ pm, const float* __restrict__ pv,
    const float* __restrict__ auxf, int K, int Nloc)
{
  const int gx = gridDim.x;
  const int nwg = gx * gridDim.y;
  int lin = blockIdx.y * gx + blockIdx.x;
  lin = (lin & 7) * (nwg >> 3) + (lin >> 3);
  const int m0 = (lin / gx) * BM, n0 = (lin % gx) * BN;

  __shared__ u16 As[BM * BK];
  __shared__ u16 Bs[BN * BK];
  const int tid = threadIdx.x;
  const int wave = tid >> 6, lane = tid & 63;

  const int eA0 = wave * 512 + lane * 8;
  const int eA1 = eA0 + 2048;
  const u16* gA0 = A + (size_t)(m0 + (eA0 >> 5)) * K + (eA0 & 31);
  const u16* gA1 = A + (size_t)(m0 + (eA1 >> 5)) * K + (eA1 & 31);
  const u16* gB0 = Bt + (size_t)(n0 + (eA0 >> 5)) * K + (eA0 & 31);
  const u16* gB1 = Bt + (size_t)(n0 + (eA1 >> 5)) * K + (eA1 & 31);
  u16* lA0 = &As[wave * 512];
  u16* lA1 = &As[wave * 512 + 2048];
  u16* lB0 = &Bs[wave * 512];
  u16* lB1 = &Bs[wave * 512 + 2048];

  f32x4 acc[4][4];
#pragma unroll
  for (int i = 0; i < 4; ++i)
#pragma unroll
    for (int j = 0; j < 4; ++j) acc[i][j] = f32x4{0.f, 0.f, 0.f, 0.f};

  const int wr = wave >> 1, wc = wave & 1;
  const int l15 = lane & 15, kb = (lane >> 4) * 8;

  for (int kt = 0; kt < K; kt += BK) {
    gload_lds16(gA0, lA0); gload_lds16(gA1, lA1);
    gload_lds16(gB0, lB0); gload_lds16(gB1, lB1);
    gA0 += BK; gA1 += BK; gB0 += BK; gB1 += BK;
    __syncthreads();
    bf16x8 af[4], bfr[4];
#pragma unroll
    for (int f = 0; f < 4; ++f) {
      af[f]  = *(const bf16x8*)&As[(wr * 64 + f * 16 + l15) * BK + kb];
      bfr[f] = *(const bf16x8*)&Bs[(wc * 64 + f * 16 + l15) * BK + kb];
    }
#pragma unroll
    for (int fm = 0; fm < 4; ++fm)
#pragma unroll
      for (int fn = 0; fn < 4; ++fn)
        acc[fm][fn] = __builtin_amdgcn_mfma_f32_16x16x32_bf16(
            af[fm], bfr[fn], acc[fm][fn], 0, 0, 0);
    __syncthreads();
  }

  const int rowb = m0 + wr * 64 + (lane >> 4) * 4;
#pragma unroll
  for (int fn = 0; fn < 4; ++fn) {
    const int col = n0 + wc * 64 + fn * 16 + l15;
    const float sc = pg[col] * rsqrtf(pv[col] + EPSB);
    const float off = pb[col] - pm[col] * sc;
#pragma unroll
    for (int fm = 0; fm < 4; ++fm) {
      const int row = rowb + fm * 16;
      if (MODE == 3) {
        const int bimg = row >> 8, p0 = row & 255;
        const size_t oa = (size_t)bimg * (COUT * NPIX) + (size_t)col * NPIX + p0;
        const float4 rv = *(const float4*)&auxf[oa];
        float4 ov;
        ov.x = fmaxf(acc[fm][fn][0] * sc + off + rv.x, 0.f);
        ov.y = fmaxf(acc[fm][fn][1] * sc + off + rv.y, 0.f);
        ov.z = fmaxf(acc[fm][fn][2] * sc + off + rv.z, 0.f);
        ov.w = fmaxf(acc[fm][fn][3] * sc + off + rv.w, 0.f);
        *(float4*)&out32[oa] = ov;
      } else {
#pragma unroll
        for (int r = 0; r < 4; ++r) {
          const float y = fmaxf(acc[fm][fn][r] * sc + off, 0.f);
          out16[(size_t)(row + r) * Nloc + col] = f2b(y);
        }
      }
    }
  }
}

// ---------- P[s][h][c] = sum_t w_gat[c][h*512+t] * att_s[h][t] (fp32) ------
__global__ __launch_bounds__(256) void attproj_kernel(
    const float* __restrict__ w_gat, const float* __restrict__ att_src,
    const float* __restrict__ att_dst, float* __restrict__ P)
{
  __shared__ float av[CRED];
  const int sh = blockIdx.x;
  const int s = sh >> 3, h = sh & 7;
  const float* att = (s == 0) ? att_src : att_dst;
  for (int t = threadIdx.x; t < CRED; t += 256) av[t] = att[h * CRED + t];
  __syncthreads();
#pragma unroll
  for (int half = 0; half < 2; ++half) {
    const int c = threadIdx.x + half * 256;
    const float* wrow = w_gat + (size_t)c * KGAT + h * CRED;
    float acc = 0.f;
    for (int j = 0; j < CRED; j += 4) {
      const float4 w = *(const float4*)&wrow[j];
      acc += w.x * av[j] + w.y * av[j + 1] + w.z * av[j + 2] + w.w * av[j + 3];
    }
    P[(size_t)sh * CRED + c] = acc;
  }
}

// ---------- a_all[s][n][h] = xr[n] . P[s][h]   (one wave per node) ---------
__global__ __launch_bounds__(256) void att_kernel(
    const u16* __restrict__ xr, const float* __restrict__ P,
    float* __restrict__ a_all)
{
  const int wave = threadIdx.x >> 6, lane = threadIdx.x & 63;
  const int m = blockIdx.x * 4 + wave;
  const int sh = lane & 15, q = lane >> 4;
  const u16* xp = xr + (size_t)m * CRED + q * 128;
  const float* Pp = P + (size_t)sh * CRED + q * 128;
  float s = 0.f;
#pragma unroll
  for (int c = 0; c < 128; c += 8) {
    u16x8 xv = *(const u16x8*)&xp[c];
#pragma unroll
    for (int t = 0; t < 8; ++t) s += b2f(xv[t]) * Pp[c + t];
  }
  s += __shfl_xor(s, 16);
  s += __shfl_xor(s, 32);
  if (q == 0)
    a_all[(size_t)(sh >> 3) * MTOT * HEADS + (size_t)m * HEADS + (sh & 7)] = s;
}

// ---------------------------------------------------------------------------
extern "C" void kernel_launch(void* const* d_in, const int* in_sizes, int n_in,
                              void* d_out, int out_size, void* d_ws, size_t ws_size,
                              hipStream_t stream)
{
  const float* x         = (const float*)d_in[0];
  const float* w_reduce  = (const float*)d_in[1];
  const float* g_red     = (const float*)d_in[2];
  const float* b_red     = (const float*)d_in[3];
  const float* m_red     = (const float*)d_in[4];
  const float* v_red     = (const float*)d_in[5];
  const float* w_gat     = (const float*)d_in[6];
  const float* att_src   = (const float*)d_in[7];
  const float* att_dst   = (const float*)d_in[8];
  const float* gat_bias  = (const float*)d_in[9];
  const float* w_restore = (const float*)d_in[10];
  const float* g_res     = (const float*)d_in[11];
  const float* b_res     = (const float*)d_in[12];
  const float* m_res     = (const float*)d_in[13];
  const float* v_res     = (const float*)d_in[14];

  constexpr size_t SZ_XT   = (size_t)MTOT * CIN * 2;   // 33,554,432
  constexpr size_t SZ_XR   = (size_t)MTOT * CRED * 2;  // 16,777,216
  constexpr size_t SZ_GAT  = SZ_XR;
  constexpr size_t SZ_WGT  = (size_t)KGAT * CRED * 2;  //  4,194,304
  constexpr size_t SZ_WRD  = (size_t)CRED * CIN * 2;
  constexpr size_t SZ_WRS  = (size_t)COUT * CRED * 2;
  constexpr size_t SZ_P    = (size_t)16 * CRED * 4;
  char* ws = (char*)d_ws;
  u16*   xt     = (u16*)ws;
  u16*   xr     = (u16*)(ws + SZ_XT);
  u16*   gat    = (u16*)(ws + SZ_XT + SZ_XR);
  u16*   WgT2   = (u16*)(ws + SZ_XT + SZ_XR + SZ_GAT);
  u16*   wred_b = (u16*)(ws + SZ_XT + SZ_XR + SZ_GAT + SZ_WGT);
  u16*   wres_b = (u16*)(ws + SZ_XT + SZ_XR + SZ_GAT + SZ_WGT + SZ_WRD);
  float* P      = (float*)(ws + SZ_XT + SZ_XR + SZ_GAT + SZ_WGT + SZ_WRD + SZ_WRS);
  float* a_all  = (float*)(ws + SZ_XT + SZ_XR + SZ_GAT + SZ_WGT + SZ_WRD + SZ_WRS + SZ_P);
  float* outp   = (float*)d_out;

  hipFuncSetAttribute((const void*)yagg_kernel,
                      hipFuncAttributeMaxDynamicSharedMemorySize, 131072);

  trcvt_kernel<<<dim3(4, 16, 64), 256, 0, stream>>>(
      x, xt, NPIX, CIN, (long)CIN * NPIX, (long)CIN * NPIX);
  trcvt_kernel<<<dim3(64, 8, 1), 256, 0, stream>>>(
      w_gat, WgT2, KGAT, CRED, 0, 0);
  cvt_kernel<<<(CRED * CIN) / 2048, 256, 0, stream>>>(w_reduce, wred_b);
  cvt_kernel<<<(COUT * CRED) / 2048, 256, 0, stream>>>(w_restore, wres_b);
  gemm_kernel<1><<<dim3(4, 128), 256, 0, stream>>>(
      xt, wred_b, xr, nullptr, g_red, b_red, m_red, v_red, nullptr, CIN, CRED);
  attproj_kernel<<<16, 256, 0, stream>>>(w_gat, att_src, att_dst, P);
  att_kernel<<<MTOT / 4, 256, 0, stream>>>(xr, P, a_all);
  yagg_kernel<<<512, 512, 118784, stream>>>(xr, WgT2, a_all, gat_bias, gat);
  gemm_kernel<3><<<dim3(8, 128), 256, 0, stream>>>(
      gat, wres_b, nullptr, outp, g_res, b_res, m_res, v_res, x, CRED, COUT);
  (void)in_sizes; (void)n_in; (void)out_size; (void)ws_size;
}